// Round 5
// baseline (211.968 us; speedup 1.0000x reference)
//
#include <hip/hip_runtime.h>

namespace {
constexpr int B = 2, C = 72, O = 72, H = 180, W = 320;
constexpr int K = 9, G = 9, Cg = 8, Og = 8;
constexpr int OFFC = 2 * K;           // 18 offset channels
constexpr int HW = H * W;             // 57600
constexpr size_t OFF_ELEMS = (size_t)B * OFFC * HW;   // 2,073,600 floats
constexpr int W1_ELEMS = OFFC * C * 9;                // 11664
constexpr int W2_ELEMS = O * Cg * 9;                  // 5184
constexpr int ICW = C / 4;            // 18 input channels per wave

// 8-byte vector load with only 4-byte alignment guarantee (gfx9+ supports
// misaligned global dwordx2; LLVM splits it if not).
typedef float f2u __attribute__((ext_vector_type(2), aligned(4)));
}

// ---------------------------------------------------------------------------
// Setup: transpose weights for contiguous wave-uniform (scalar) access.
//   w1t[ic][tap][oc]   <- off_w[oc][ic][tap]      (18,72,3,3)
//   w2t[g][k][cg][og]  <- weight[g*8+og][cg][k]   (72,8,3,3)
// ---------------------------------------------------------------------------
__global__ __launch_bounds__(256) void transpose_weights(
    const float* __restrict__ off_w,
    const float* __restrict__ weight,
    float* __restrict__ w1t,
    float* __restrict__ w2t)
{
    int i = blockIdx.x * blockDim.x + threadIdx.x;
    if (i < W1_ELEMS) {
        int oc = i % OFFC;
        int tap = (i / OFFC) % 9;
        int ic = i / (OFFC * 9);
        w1t[i] = off_w[(oc * C + ic) * 9 + tap];
    }
    if (i < W2_ELEMS) {
        int og = i % Og;
        int cg = (i / Og) % Cg;
        int k = (i / (Og * Cg)) % K;
        int g = i / (Og * Cg * K);
        w2t[i] = weight[((g * Og + og) * Cg + cg) * 9 + k];
    }
}

// ---------------------------------------------------------------------------
// Kernel 1: 3x3 conv (C=72 -> 18) + bias. 4 waves split C; LDS reduce.
// ic0 via readfirstlane -> provably wave-uniform weight addrs -> s_load.
// ---------------------------------------------------------------------------
__global__ __launch_bounds__(256, 8) void offset_conv(
    const float* __restrict__ x,      // (B, C, H, W) = offset_feat
    const float* __restrict__ w1t,    // [ic][tap][oc]
    const float* __restrict__ bias,   // (18,)
    float* __restrict__ offs)         // (B, 18, H, W)
{
    __shared__ float red[4 * 64 * OFFC];   // 18432 B
    const int lane = threadIdx.x & 63;
    const int wave = threadIdx.x >> 6;

    const int g0 = blockIdx.x * 64;        // pixel index over B*HW
    const int b = g0 / HW;
    const int pix = g0 - b * HW;           // multiple of 64; one row segment
    const int yh = pix / W;
    const int x0b = pix - yh * W;
    const int xw = x0b + lane;

    float acc[OFFC];
    #pragma unroll
    for (int oc = 0; oc < OFFC; ++oc) acc[oc] = 0.f;

    const float* xb = x + (size_t)b * C * HW;
    const int ic0 = __builtin_amdgcn_readfirstlane(wave * ICW);

    const bool rv0 = (yh - 1) >= 0;
    const bool rv2 = (yh + 1) < H;

    #pragma unroll 3
    for (int ici = 0; ici < ICW; ++ici) {
        const int ic = ic0 + ici;
        const float* xc = xb + ic * HW;
        #pragma unroll
        for (int ky = 0; ky < 3; ++ky) {
            const int yy = yh + ky - 1;
            const bool rowv = (ky == 0) ? rv0 : (ky == 2 ? rv2 : true);
            if (!rowv) continue;           // uniform branch
            const float* xr = xc + yy * W;
            #pragma unroll
            for (int kx = 0; kx < 3; ++kx) {
                const int xx = xw + kx - 1;
                const bool v = (xx >= 0) & (xx < W);
                const float val = v ? xr[xx] : 0.0f;
                const float* wp = w1t + (ic * 9 + ky * 3 + kx) * OFFC;
                #pragma unroll
                for (int oc = 0; oc < OFFC; ++oc)
                    acc[oc] = fmaf(val, wp[oc], acc[oc]);
            }
        }
    }

    #pragma unroll
    for (int oc = 0; oc < OFFC; ++oc)
        red[(wave * 64 + lane) * OFFC + oc] = acc[oc];
    __syncthreads();

    for (int e = threadIdx.x; e < 64 * OFFC; e += 256) {
        const int oc = e / 64;
        const int px = e - oc * 64;
        float s = bias[oc];
        #pragma unroll
        for (int w = 0; w < 4; ++w)
            s += red[(w * 64 + px) * OFFC + oc];
        offs[(size_t)b * OFFC * HW + (size_t)oc * HW + pix + px] = s;
    }
}

// ---------------------------------------------------------------------------
// Kernel 2: deformable grouped conv. One thread per (pixel, group).
// Round 5: (a) launch_bounds(256,8) caps VGPR at 64 -> 8 waves/SIMD
// (round 4's 68 VGPR halved occupancy); (b) bilinear+clamp+validity folded
// into 4 per-tap pair-weights w00..w11 (wave-width, once per tap) so the
// per-(tap,cg) body is one dwordx2 pair + 4-term fma chain + 8 output FMAs
// with NO cndmask: 18 -> 12 VALU.
//   pair = columns {xbase, xbase+1}, xbase = clamp(x0, 0, W-2)
//   wA = gx0*[x0c==xbase]   + gx1*[x1c==xbase]
//   wB = gx0*[x0c==xbase+1] + gx1*[x1c==xbase+1]
//   w00=hy0*wA  w01=hy0*wB  w10=hy1*wA  w11=hy1*wB
// Cases: interior -> (wx0,wx1); x0=-1 -> wA=wx1,wB=0; x0=W-1 -> wA=0,wB=wx0;
// fully OOB -> zeros. Clamped rows read real in-bounds floats * weight 0.
// ---------------------------------------------------------------------------
__global__ __launch_bounds__(256, 8) void deform_conv(
    const float* __restrict__ x,      // (B, C, H, W) = input
    const float* __restrict__ offs,   // (B, 18, H, W)
    const float* __restrict__ w2t,    // [g][k][cg][og]
    float* __restrict__ out)          // (B, O, H, W)
{
    int idx = blockIdx.x * blockDim.x + threadIdx.x;
    int xw = idx % W;
    int yh = (idx / W) % H;
    int g = (idx / HW) % G;
    int b = idx / (HW * G);

    int gu = __builtin_amdgcn_readfirstlane(g);
    const float* wg = w2t + gu * (K * Cg * Og);
    const float* xg = x + ((size_t)b * C + gu * Cg) * HW;
    const float* offp = offs + (size_t)b * OFFC * HW + yh * W + xw;

    // Hoist all offset loads: 18 coalesced loads in flight at once.
    float dy[K], dx[K];
    #pragma unroll
    for (int k = 0; k < K; ++k) {
        dy[k] = offp[(size_t)(2 * k) * HW];
        dx[k] = offp[(size_t)(2 * k + 1) * HW];
    }

    float acc[Og];
    #pragma unroll
    for (int og = 0; og < Og; ++og) acc[og] = 0.f;

    #pragma unroll
    for (int k = 0; k < K; ++k) {
        float py = (float)(yh + k / 3 - 1) + dy[k];
        float px = (float)(xw + k % 3 - 1) + dx[k];
        float fy = floorf(py);
        float fx = floorf(px);
        int y0 = (int)fy, x0 = (int)fx;
        float wy1 = py - fy, wx1 = px - fx;
        float wy0 = 1.f - wy1, wx0 = 1.f - wx1;
        // validity folded into weights (invalid taps contribute 0)
        float hy0 = ((y0 >= 0) & (y0 < H)) ? wy0 : 0.f;
        float hy1 = ((y0 + 1 >= 0) & (y0 + 1 < H)) ? wy1 : 0.f;
        float gx0 = ((x0 >= 0) & (x0 < W)) ? wx0 : 0.f;
        float gx1 = ((x0 + 1 >= 0) & (x0 + 1 < W)) ? wx1 : 0.f;
        int y0c = min(max(y0, 0), H - 1);
        int y1c = min(max(y0 + 1, 0), H - 1);
        int x0c = min(max(x0, 0), W - 1);
        int x1c = min(max(x0 + 1, 0), W - 1);
        int xbase = min(max(x0, 0), W - 2);     // pair {xbase, xbase+1}
        // fold column-select into pair weights (once per tap, not per cg)
        float wA = (x0c == xbase ? gx0 : 0.f) + (x1c == xbase ? gx1 : 0.f);
        float wB = (x0c == xbase + 1 ? gx0 : 0.f) + (x1c == xbase + 1 ? gx1 : 0.f);
        float w00 = hy0 * wA, w01 = hy0 * wB;
        float w10 = hy1 * wA, w11 = hy1 * wB;
        int r0 = y0c * W + xbase;
        int r1 = y1c * W + xbase;
        const float* wk = wg + k * (Cg * Og);
        #pragma unroll
        for (int cg = 0; cg < Cg; ++cg) {
            const float* xc = xg + cg * HW;
            f2u a0 = *(const f2u*)(xc + r0);
            f2u a1 = *(const f2u*)(xc + r1);
            float v = w00 * a0.x;
            v = fmaf(w01, a0.y, v);
            v = fmaf(w10, a1.x, v);
            v = fmaf(w11, a1.y, v);
            #pragma unroll
            for (int og = 0; og < Og; ++og)
                acc[og] = fmaf(v, wk[cg * Og + og], acc[og]);
        }
    }
    float* op = out + ((size_t)b * O + gu * Og) * HW + yh * W + xw;
    #pragma unroll
    for (int og = 0; og < Og; ++og) op[(size_t)og * HW] = acc[og];
}

extern "C" void kernel_launch(void* const* d_in, const int* in_sizes, int n_in,
                              void* d_out, int out_size, void* d_ws, size_t ws_size,
                              hipStream_t stream) {
    const float* input       = (const float*)d_in[0];
    const float* offset_feat = (const float*)d_in[1];
    const float* weight      = (const float*)d_in[2];
    const float* off_w       = (const float*)d_in[3];
    const float* off_b       = (const float*)d_in[4];
    float* out = (float*)d_out;

    float* offs = (float*)d_ws;
    float* w1t = offs + OFF_ELEMS;
    float* w2t = w1t + W1_ELEMS;

    transpose_weights<<<(W1_ELEMS + 255) / 256, 256, 0, stream>>>(off_w, weight, w1t, w2t);
    offset_conv<<<(B * HW) / 64, 256, 0, stream>>>(offset_feat, w1t, off_b, offs);
    deform_conv<<<(B * G * HW) / 256, 256, 0, stream>>>(input, offs, w2t, out);
}

// Round 6
// 139.783 us; speedup vs baseline: 1.5164x; 1.5164x over previous
//
#include <hip/hip_runtime.h>

namespace {
constexpr int B = 2, C = 72, O = 72, H = 180, W = 320;
constexpr int K = 9, G = 9, Cg = 8, Og = 8;
constexpr int OFFC = 2 * K;           // 18 offset channels
constexpr int HW = H * W;             // 57600
constexpr size_t OFF_ELEMS = (size_t)B * OFFC * HW;   // 2,073,600 floats
constexpr int W1_ELEMS = OFFC * C * 9;                // 11664
constexpr int W2_ELEMS = O * Cg * 9;                  // 5184
constexpr int ICW = C / 4;            // 18 input channels per wave

// deform tile geometry: one block = one group x (64 wide x 4 tall) pixels
constexpr int TW = 64, TH = 4;
constexpr int HALO = 5;               // supports |offset| <= ~4 before fallback
constexpr int NR = TH + 2 * HALO;     // 14 staged rows
constexpr int NC = TW + 2 * HALO;     // 74 staged cols
constexpr int TX = W / TW;            // 5
constexpr int TY = H / TH;            // 45

typedef float f2u __attribute__((ext_vector_type(2), aligned(4)));
}

// ---------------------------------------------------------------------------
// Setup: transpose weights for contiguous wave-uniform (scalar) access.
// ---------------------------------------------------------------------------
__global__ __launch_bounds__(256) void transpose_weights(
    const float* __restrict__ off_w,
    const float* __restrict__ weight,
    float* __restrict__ w1t,
    float* __restrict__ w2t)
{
    int i = blockIdx.x * blockDim.x + threadIdx.x;
    if (i < W1_ELEMS) {
        int oc = i % OFFC;
        int tap = (i / OFFC) % 9;
        int ic = i / (OFFC * 9);
        w1t[i] = off_w[(oc * C + ic) * 9 + tap];
    }
    if (i < W2_ELEMS) {
        int og = i % Og;
        int cg = (i / Og) % Cg;
        int k = (i / (Og * Cg)) % K;
        int g = i / (Og * Cg * K);
        w2t[i] = weight[((g * Og + og) * Cg + cg) * 9 + k];
    }
}

// ---------------------------------------------------------------------------
// Kernel 1: 3x3 conv (C=72 -> 18) + bias. 4 waves split C; LDS reduce.
// (unchanged; ~30us, not the current bottleneck)
// ---------------------------------------------------------------------------
__global__ __launch_bounds__(256, 8) void offset_conv(
    const float* __restrict__ x,
    const float* __restrict__ w1t,
    const float* __restrict__ bias,
    float* __restrict__ offs)
{
    __shared__ float red[4 * 64 * OFFC];
    const int lane = threadIdx.x & 63;
    const int wave = threadIdx.x >> 6;

    const int g0 = blockIdx.x * 64;
    const int b = g0 / HW;
    const int pix = g0 - b * HW;
    const int yh = pix / W;
    const int x0b = pix - yh * W;
    const int xw = x0b + lane;

    float acc[OFFC];
    #pragma unroll
    for (int oc = 0; oc < OFFC; ++oc) acc[oc] = 0.f;

    const float* xb = x + (size_t)b * C * HW;
    const int ic0 = __builtin_amdgcn_readfirstlane(wave * ICW);

    const bool rv0 = (yh - 1) >= 0;
    const bool rv2 = (yh + 1) < H;

    #pragma unroll 3
    for (int ici = 0; ici < ICW; ++ici) {
        const int ic = ic0 + ici;
        const float* xc = xb + ic * HW;
        #pragma unroll
        for (int ky = 0; ky < 3; ++ky) {
            const int yy = yh + ky - 1;
            const bool rowv = (ky == 0) ? rv0 : (ky == 2 ? rv2 : true);
            if (!rowv) continue;
            const float* xr = xc + yy * W;
            #pragma unroll
            for (int kx = 0; kx < 3; ++kx) {
                const int xx = xw + kx - 1;
                const bool v = (xx >= 0) & (xx < W);
                const float val = v ? xr[xx] : 0.0f;
                const float* wp = w1t + (ic * 9 + ky * 3 + kx) * OFFC;
                #pragma unroll
                for (int oc = 0; oc < OFFC; ++oc)
                    acc[oc] = fmaf(val, wp[oc], acc[oc]);
            }
        }
    }

    #pragma unroll
    for (int oc = 0; oc < OFFC; ++oc)
        red[(wave * 64 + lane) * OFFC + oc] = acc[oc];
    __syncthreads();

    for (int e = threadIdx.x; e < 64 * OFFC; e += 256) {
        const int oc = e / 64;
        const int px = e - oc * 64;
        float s = bias[oc];
        #pragma unroll
        for (int w = 0; w < 4; ++w)
            s += red[(w * 64 + px) * OFFC + oc];
        offs[(size_t)b * OFFC * HW + (size_t)oc * HW + pix + px] = s;
    }
}

// ---------------------------------------------------------------------------
// Kernel 2: deformable grouped conv with EXPLICIT LDS reuse.
// Block = (b, g, 4x64 pixel tile). Stage 8 channels x 14 rows x 74 cols
// (halo +-5, clamped sources -> always-valid addresses; out-of-image slots
// hold duplicates that are never read because gather indices are clamped
// into the image). Bilinear gathers read LDS; any sample whose 2x2 footprint
// falls outside the staged window takes an exact global-memory fallback.
// This converts ~144 scattered VMEM gathers/thread into ~33 coalesced
// staging loads + LDS reads, making the 36x input reuse explicit instead of
// relying on L2 (which R5 showed thrashing: FETCH 146->447 MB).
// ---------------------------------------------------------------------------
__global__ __launch_bounds__(256) void deform_conv(
    const float* __restrict__ x,      // (B, C, H, W)
    const float* __restrict__ offs,   // (B, 18, H, W)
    const float* __restrict__ w2t,    // [g][k][cg][og]
    float* __restrict__ out)          // (B, O, H, W)
{
    __shared__ float sm[Cg * NR * NC];     // 33,152 B

    const int bi = blockIdx.x;
    const int tx = bi % TX;
    const int ty = (bi / TX) % TY;
    const int g  = (bi / (TX * TY)) % G;
    const int b  = bi / (TX * TY * G);

    const int lane = threadIdx.x & 63;
    const int wrow = threadIdx.x >> 6;
    const int xw = tx * TW + lane;
    const int yh = ty * TH + wrow;

    const int gu = __builtin_amdgcn_readfirstlane(g);
    const float* wg = w2t + gu * (K * Cg * Og);
    const float* xg = x + ((size_t)b * C + gu * Cg) * HW;
    const float* offp = offs + (size_t)b * OFFC * HW + yh * W + xw;

    // Hoist offset loads (in flight while we stage).
    float dy[K], dx[K];
    #pragma unroll
    for (int k = 0; k < K; ++k) {
        dy[k] = offp[(size_t)(2 * k) * HW];
        dx[k] = offp[(size_t)(2 * k + 1) * HW];
    }

    // Stage window: nominal rows [wy, wy+NR), cols [wx, wx+NC).
    const int wy = ty * TH - HALO;
    const int wx = tx * TW - HALO;
    for (int e = threadIdx.x; e < Cg * NR * NC; e += 256) {
        const int c  = e % NC;
        const int rr = (e / NC) % NR;
        const int ch = e / (NC * NR);
        const int sy = min(max(wy + rr, 0), H - 1);
        const int sx = min(max(wx + c, 0), W - 1);
        sm[e] = xg[ch * HW + sy * W + sx];
    }
    __syncthreads();

    float acc[Og];
    #pragma unroll
    for (int og = 0; og < Og; ++og) acc[og] = 0.f;

    #pragma unroll
    for (int k = 0; k < K; ++k) {
        float py = (float)(yh + k / 3 - 1) + dy[k];
        float px = (float)(xw + k % 3 - 1) + dx[k];
        float fy = floorf(py);
        float fx = floorf(px);
        int y0 = (int)fy, x0 = (int)fx;
        float wy1 = py - fy, wx1 = px - fx;
        float wy0 = 1.f - wy1, wx0 = 1.f - wx1;
        float hy0 = ((y0 >= 0) & (y0 < H)) ? wy0 : 0.f;
        float hy1 = ((y0 + 1 >= 0) & (y0 + 1 < H)) ? wy1 : 0.f;
        float gx0 = ((x0 >= 0) & (x0 < W)) ? wx0 : 0.f;
        float gx1 = ((x0 + 1 >= 0) & (x0 + 1 < W)) ? wx1 : 0.f;
        int y0c = min(max(y0, 0), H - 1);
        int y1c = min(max(y0 + 1, 0), H - 1);
        int x0c = min(max(x0, 0), W - 1);
        int x1c = min(max(x0 + 1, 0), W - 1);
        int xbase = min(max(x0, 0), W - 2);
        float wA = (x0c == xbase ? gx0 : 0.f) + (x1c == xbase ? gx1 : 0.f);
        float wB = (x0c == xbase + 1 ? gx0 : 0.f) + (x1c == xbase + 1 ? gx1 : 0.f);
        float w00 = hy0 * wA, w01 = hy0 * wB;
        float w10 = hy1 * wA, w11 = hy1 * wB;
        const float* wk = wg + k * (Cg * Og);

        const int lr0 = y0c - wy;
        const int lr1 = y1c - wy;
        const int lcb = xbase - wx;
        const bool inw = ((unsigned)lr0 < NR) & ((unsigned)lr1 < NR) &
                         ((unsigned)lcb < (NC - 1));
        if (inw) {
            const float* s0 = sm + lr0 * NC + lcb;
            const float* s1 = sm + lr1 * NC + lcb;
            #pragma unroll
            for (int cg = 0; cg < Cg; ++cg) {
                const int o = cg * (NR * NC);
                float v = w00 * s0[o];
                v = fmaf(w01, s0[o + 1], v);
                v = fmaf(w10, s1[o], v);
                v = fmaf(w11, s1[o + 1], v);
                #pragma unroll
                for (int og = 0; og < Og; ++og)
                    acc[og] = fmaf(v, wk[cg * Og + og], acc[og]);
            }
        } else {
            const int r0 = y0c * W + xbase;
            const int r1 = y1c * W + xbase;
            #pragma unroll
            for (int cg = 0; cg < Cg; ++cg) {
                const float* xc = xg + cg * HW;
                f2u a0 = *(const f2u*)(xc + r0);
                f2u a1 = *(const f2u*)(xc + r1);
                float v = w00 * a0.x;
                v = fmaf(w01, a0.y, v);
                v = fmaf(w10, a1.x, v);
                v = fmaf(w11, a1.y, v);
                #pragma unroll
                for (int og = 0; og < Og; ++og)
                    acc[og] = fmaf(v, wk[cg * Og + og], acc[og]);
            }
        }
    }
    float* op = out + ((size_t)b * O + gu * Og) * HW + yh * W + xw;
    #pragma unroll
    for (int og = 0; og < Og; ++og) op[(size_t)og * HW] = acc[og];
}

extern "C" void kernel_launch(void* const* d_in, const int* in_sizes, int n_in,
                              void* d_out, int out_size, void* d_ws, size_t ws_size,
                              hipStream_t stream) {
    const float* input       = (const float*)d_in[0];
    const float* offset_feat = (const float*)d_in[1];
    const float* weight      = (const float*)d_in[2];
    const float* off_w       = (const float*)d_in[3];
    const float* off_b       = (const float*)d_in[4];
    float* out = (float*)d_out;

    float* offs = (float*)d_ws;
    float* w1t = offs + OFF_ELEMS;
    float* w2t = w1t + W1_ELEMS;

    transpose_weights<<<(W1_ELEMS + 255) / 256, 256, 0, stream>>>(off_w, weight, w1t, w2t);
    offset_conv<<<(B * HW) / 64, 256, 0, stream>>>(offset_feat, w1t, off_b, offs);
    deform_conv<<<B * G * TX * TY, 256, 0, stream>>>(input, offs, w2t, out);
}

// Round 7
// 108.944 us; speedup vs baseline: 1.9457x; 1.2831x over previous
//
#include <hip/hip_runtime.h>

namespace {
constexpr int B = 2, C = 72, O = 72, H = 180, W = 320;
constexpr int K = 9, G = 9, Cg = 8, Og = 8;
constexpr int OFFC = 2 * K;           // 18 offset channels
constexpr int HW = H * W;             // 57600
constexpr size_t OFF_ELEMS = (size_t)B * OFFC * HW;   // 2,073,600 floats
constexpr int W1_ELEMS = OFFC * C * 9;                // 11664
constexpr int W2_ELEMS = O * Cg * 9;                  // 5184
constexpr int ICW = C / 4;            // 18 input channels per wave

// deform tile geometry: one block = one group x (64 wide x 4 tall) pixels
constexpr int TW = 64, TH = 4;
// Offsets are statistically tiny: dy,dx ~ N(0, ~0.26) (conv of N(0,1) feat
// with 0.01-scale weights over 648 taps). HALO=2 covers tap(+-1) + offset
// (+-~1) + bilinear(+1); the exact global fallback absorbs the ~1e-4 tail.
// LDS: 8ch x 8r x 68c x 4B = 17,408 B -> 9 blocks/CU -> 32-wave cap.
constexpr int HALO = 2;
constexpr int NR = TH + 2 * HALO;     // 8 staged rows
constexpr int NC = TW + 2 * HALO;     // 68 staged cols
constexpr int TX = W / TW;            // 5
constexpr int TY = H / TH;            // 45

typedef float f2u __attribute__((ext_vector_type(2), aligned(4)));
}

// ---------------------------------------------------------------------------
// Setup: transpose weights for contiguous wave-uniform (scalar) access.
// ---------------------------------------------------------------------------
__global__ __launch_bounds__(256) void transpose_weights(
    const float* __restrict__ off_w,
    const float* __restrict__ weight,
    float* __restrict__ w1t,
    float* __restrict__ w2t)
{
    int i = blockIdx.x * blockDim.x + threadIdx.x;
    if (i < W1_ELEMS) {
        int oc = i % OFFC;
        int tap = (i / OFFC) % 9;
        int ic = i / (OFFC * 9);
        w1t[i] = off_w[(oc * C + ic) * 9 + tap];
    }
    if (i < W2_ELEMS) {
        int og = i % Og;
        int cg = (i / Og) % Cg;
        int k = (i / (Og * Cg)) % K;
        int g = i / (Og * Cg * K);
        w2t[i] = weight[((g * Og + og) * Cg + cg) * 9 + k];
    }
}

// ---------------------------------------------------------------------------
// Kernel 1: 3x3 conv (C=72 -> 18) + bias. 4 waves split C; LDS reduce.
// ic0 via readfirstlane -> provably wave-uniform weight addrs -> s_load.
// ---------------------------------------------------------------------------
__global__ __launch_bounds__(256, 8) void offset_conv(
    const float* __restrict__ x,
    const float* __restrict__ w1t,
    const float* __restrict__ bias,
    float* __restrict__ offs)
{
    __shared__ float red[4 * 64 * OFFC];
    const int lane = threadIdx.x & 63;
    const int wave = threadIdx.x >> 6;

    const int g0 = blockIdx.x * 64;
    const int b = g0 / HW;
    const int pix = g0 - b * HW;
    const int yh = pix / W;
    const int x0b = pix - yh * W;
    const int xw = x0b + lane;

    float acc[OFFC];
    #pragma unroll
    for (int oc = 0; oc < OFFC; ++oc) acc[oc] = 0.f;

    const float* xb = x + (size_t)b * C * HW;
    const int ic0 = __builtin_amdgcn_readfirstlane(wave * ICW);

    const bool rv0 = (yh - 1) >= 0;
    const bool rv2 = (yh + 1) < H;

    #pragma unroll 3
    for (int ici = 0; ici < ICW; ++ici) {
        const int ic = ic0 + ici;
        const float* xc = xb + ic * HW;
        #pragma unroll
        for (int ky = 0; ky < 3; ++ky) {
            const int yy = yh + ky - 1;
            const bool rowv = (ky == 0) ? rv0 : (ky == 2 ? rv2 : true);
            if (!rowv) continue;
            const float* xr = xc + yy * W;
            #pragma unroll
            for (int kx = 0; kx < 3; ++kx) {
                const int xx = xw + kx - 1;
                const bool v = (xx >= 0) & (xx < W);
                const float val = v ? xr[xx] : 0.0f;
                const float* wp = w1t + (ic * 9 + ky * 3 + kx) * OFFC;
                #pragma unroll
                for (int oc = 0; oc < OFFC; ++oc)
                    acc[oc] = fmaf(val, wp[oc], acc[oc]);
            }
        }
    }

    #pragma unroll
    for (int oc = 0; oc < OFFC; ++oc)
        red[(wave * 64 + lane) * OFFC + oc] = acc[oc];
    __syncthreads();

    for (int e = threadIdx.x; e < 64 * OFFC; e += 256) {
        const int oc = e / 64;
        const int px = e - oc * 64;
        float s = bias[oc];
        #pragma unroll
        for (int w = 0; w < 4; ++w)
            s += red[(w * 64 + px) * OFFC + oc];
        offs[(size_t)b * OFFC * HW + (size_t)oc * HW + pix + px] = s;
    }
}

// ---------------------------------------------------------------------------
// Kernel 2: deformable grouped conv with explicit LDS reuse (R6 structure,
// R7: HALO 5->2 -> LDS 33.3->17.4 KB -> 9 blocks/CU, wave cap 16->32;
// halo duplication 4.05x->2.13x so HBM fetch also drops.
// ---------------------------------------------------------------------------
__global__ __launch_bounds__(256) void deform_conv(
    const float* __restrict__ x,      // (B, C, H, W)
    const float* __restrict__ offs,   // (B, 18, H, W)
    const float* __restrict__ w2t,    // [g][k][cg][og]
    float* __restrict__ out)          // (B, O, H, W)
{
    __shared__ float sm[Cg * NR * NC];     // 17,408 B

    const int bi = blockIdx.x;
    const int tx = bi % TX;
    const int ty = (bi / TX) % TY;
    const int g  = (bi / (TX * TY)) % G;
    const int b  = bi / (TX * TY * G);

    const int lane = threadIdx.x & 63;
    const int wrow = threadIdx.x >> 6;
    const int xw = tx * TW + lane;
    const int yh = ty * TH + wrow;

    const int gu = __builtin_amdgcn_readfirstlane(g);
    const float* wg = w2t + gu * (K * Cg * Og);
    const float* xg = x + ((size_t)b * C + gu * Cg) * HW;
    const float* offp = offs + (size_t)b * OFFC * HW + yh * W + xw;

    // Hoist offset loads (in flight while we stage).
    float dy[K], dx[K];
    #pragma unroll
    for (int k = 0; k < K; ++k) {
        dy[k] = offp[(size_t)(2 * k) * HW];
        dx[k] = offp[(size_t)(2 * k + 1) * HW];
    }

    // Stage window: nominal rows [wy, wy+NR), cols [wx, wx+NC).
    const int wy = ty * TH - HALO;
    const int wx = tx * TW - HALO;
    for (int e = threadIdx.x; e < Cg * NR * NC; e += 256) {
        const int c  = e % NC;
        const int rr = (e / NC) % NR;
        const int ch = e / (NC * NR);
        const int sy = min(max(wy + rr, 0), H - 1);
        const int sx = min(max(wx + c, 0), W - 1);
        sm[e] = xg[ch * HW + sy * W + sx];
    }
    __syncthreads();

    float acc[Og];
    #pragma unroll
    for (int og = 0; og < Og; ++og) acc[og] = 0.f;

    #pragma unroll
    for (int k = 0; k < K; ++k) {
        float py = (float)(yh + k / 3 - 1) + dy[k];
        float px = (float)(xw + k % 3 - 1) + dx[k];
        float fy = floorf(py);
        float fx = floorf(px);
        int y0 = (int)fy, x0 = (int)fx;
        float wy1 = py - fy, wx1 = px - fx;
        float wy0 = 1.f - wy1, wx0 = 1.f - wx1;
        float hy0 = ((y0 >= 0) & (y0 < H)) ? wy0 : 0.f;
        float hy1 = ((y0 + 1 >= 0) & (y0 + 1 < H)) ? wy1 : 0.f;
        float gx0 = ((x0 >= 0) & (x0 < W)) ? wx0 : 0.f;
        float gx1 = ((x0 + 1 >= 0) & (x0 + 1 < W)) ? wx1 : 0.f;
        int y0c = min(max(y0, 0), H - 1);
        int y1c = min(max(y0 + 1, 0), H - 1);
        int x0c = min(max(x0, 0), W - 1);
        int x1c = min(max(x0 + 1, 0), W - 1);
        int xbase = min(max(x0, 0), W - 2);
        float wA = (x0c == xbase ? gx0 : 0.f) + (x1c == xbase ? gx1 : 0.f);
        float wB = (x0c == xbase + 1 ? gx0 : 0.f) + (x1c == xbase + 1 ? gx1 : 0.f);
        float w00 = hy0 * wA, w01 = hy0 * wB;
        float w10 = hy1 * wA, w11 = hy1 * wB;
        const float* wk = wg + k * (Cg * Og);

        const int lr0 = y0c - wy;
        const int lr1 = y1c - wy;
        const int lcb = xbase - wx;
        const bool inw = ((unsigned)lr0 < NR) & ((unsigned)lr1 < NR) &
                         ((unsigned)lcb < (NC - 1));
        if (inw) {
            const float* s0 = sm + lr0 * NC + lcb;
            const float* s1 = sm + lr1 * NC + lcb;
            #pragma unroll
            for (int cg = 0; cg < Cg; ++cg) {
                const int o = cg * (NR * NC);
                float v = w00 * s0[o];
                v = fmaf(w01, s0[o + 1], v);
                v = fmaf(w10, s1[o], v);
                v = fmaf(w11, s1[o + 1], v);
                #pragma unroll
                for (int og = 0; og < Og; ++og)
                    acc[og] = fmaf(v, wk[cg * Og + og], acc[og]);
            }
        } else {
            const int r0 = y0c * W + xbase;
            const int r1 = y1c * W + xbase;
            #pragma unroll
            for (int cg = 0; cg < Cg; ++cg) {
                const float* xc = xg + cg * HW;
                f2u a0 = *(const f2u*)(xc + r0);
                f2u a1 = *(const f2u*)(xc + r1);
                float v = w00 * a0.x;
                v = fmaf(w01, a0.y, v);
                v = fmaf(w10, a1.x, v);
                v = fmaf(w11, a1.y, v);
                #pragma unroll
                for (int og = 0; og < Og; ++og)
                    acc[og] = fmaf(v, wk[cg * Og + og], acc[og]);
            }
        }
    }
    float* op = out + ((size_t)b * O + gu * Og) * HW + yh * W + xw;
    #pragma unroll
    for (int og = 0; og < Og; ++og) op[(size_t)og * HW] = acc[og];
}

extern "C" void kernel_launch(void* const* d_in, const int* in_sizes, int n_in,
                              void* d_out, int out_size, void* d_ws, size_t ws_size,
                              hipStream_t stream) {
    const float* input       = (const float*)d_in[0];
    const float* offset_feat = (const float*)d_in[1];
    const float* weight      = (const float*)d_in[2];
    const float* off_w       = (const float*)d_in[3];
    const float* off_b       = (const float*)d_in[4];
    float* out = (float*)d_out;

    float* offs = (float*)d_ws;
    float* w1t = offs + OFF_ELEMS;
    float* w2t = w1t + W1_ELEMS;

    transpose_weights<<<(W1_ELEMS + 255) / 256, 256, 0, stream>>>(off_w, weight, w1t, w2t);
    offset_conv<<<(B * HW) / 64, 256, 0, stream>>>(offset_feat, w1t, off_b, offs);
    deform_conv<<<B * G * TX * TY, 256, 0, stream>>>(input, offs, w2t, out);
}